// Round 4
// baseline (198.807 us; speedup 1.0000x reference)
//
#include <hip/hip_runtime.h>
#include <hip/hip_bf16.h>
#include <stdint.h>

#define BATCH 8
#define K_DIM 4096
#define N_DIM 16384
#define KH (K_DIM / 2)          // 2048 packed ints per output row
#define BLOCK 512               // 8 waves
#define ROWS_PER_WAVE 4
#define ROWS_PER_BLOCK 32       // 8 waves * 4 rows
#define ITERS (KH / 4 / 64)     // 8 iterations of int4 per lane (even)

typedef __attribute__((ext_vector_type(2))) float f32x2;

__device__ __forceinline__ float bf16lo(uint32_t u) { return __uint_as_float(u << 16); }
__device__ __forceinline__ float bf16hi(uint32_t u) { return __uint_as_float(u & 0xFFFF0000u); }

// RNE f32 -> bf16 bits (low 16)
__device__ __forceinline__ uint32_t f32_to_bf16_bits(float f) {
    uint32_t u = __float_as_uint(f);
    return (u + 0x7FFFu + ((u >> 16) & 1u)) >> 16;
}

// LDS: xchunks[phys] (uint4) = column c's 8 batches as bf16, phys = c ^ ((c>>3)&7).
// Any 8 consecutive logical columns hit all 8 quad-bank groups -> conflict-free b128.
__global__ __launch_bounds__(BLOCK, 2)   // 2 blocks/CU, <=128 VGPR
void w4a16_gemv(const float* __restrict__ x,       // [8][4096] f32 (fp16 upcast)
                const int*   __restrict__ w,       // [16384][2048] int32 (byte each)
                const float* __restrict__ scales,  // [16384] f32
                float*       __restrict__ out)     // [8][16384] f32
{
    __shared__ uint4 xchunks[K_DIM];   // 64 KiB
    const int tid = threadIdx.x;

    // ---- stage x -> LDS: one thread per column, ds_write_b128 ----
    #pragma unroll
    for (int t = 0; t < K_DIM / BLOCK; ++t) {      // 8 iterations
        const int c = t * BLOCK + tid;
        float v[BATCH];
        #pragma unroll
        for (int b = 0; b < BATCH; ++b) v[b] = x[b * K_DIM + c];
        uint4 pk;
        pk.x = f32_to_bf16_bits(v[0]) | (f32_to_bf16_bits(v[1]) << 16);
        pk.y = f32_to_bf16_bits(v[2]) | (f32_to_bf16_bits(v[3]) << 16);
        pk.z = f32_to_bf16_bits(v[4]) | (f32_to_bf16_bits(v[5]) << 16);
        pk.w = f32_to_bf16_bits(v[6]) | (f32_to_bf16_bits(v[7]) << 16);
        xchunks[c ^ ((c >> 3) & 7)] = pk;
    }
    __syncthreads();

    const int wave = tid >> 6;
    const int lane = tid & 63;
    const int row0 = blockIdx.x * ROWS_PER_BLOCK + wave * ROWS_PER_WAVE;
    const int xork = lane & 7;           // (t*64+lane)&7 is t-invariant

    const int4* __restrict__ wv0 = (const int4*)(w + (size_t)(row0 + 0) * KH);
    const int4* __restrict__ wv1 = (const int4*)(w + (size_t)(row0 + 1) * KH);
    const int4* __restrict__ wv2 = (const int4*)(w + (size_t)(row0 + 2) * KH);
    const int4* __restrict__ wv3 = (const int4*)(w + (size_t)(row0 + 3) * KH);

    f32x2 acc2[ROWS_PER_WAVE][BATCH / 2];
    #pragma unroll
    for (int j = 0; j < ROWS_PER_WAVE; ++j)
        #pragma unroll
        for (int p = 0; p < BATCH / 2; ++p) acc2[j][p] = (f32x2){0.0f, 0.0f};

    // compute step for one int4-per-row group at iteration t
    auto compute = [&](const int4 (&q)[ROWS_PER_WAVE], int t) {
        const int u     = (t << 6) + lane;
        const int cbase = u << 3;
        int qw[ROWS_PER_WAVE][4];
        #pragma unroll
        for (int j = 0; j < ROWS_PER_WAVE; ++j) {
            qw[j][0] = q[j].x; qw[j][1] = q[j].y; qw[j][2] = q[j].z; qw[j][3] = q[j].w;
        }
        #pragma unroll
        for (int m = 0; m < 4; ++m) {
            const uint4 xa = xchunks[cbase + ((2 * m)     ^ xork)];
            const uint4 xb = xchunks[cbase + ((2 * m + 1) ^ xork)];
            f32x2 xlo2[4], xhi2[4];
            xlo2[0] = (f32x2){bf16lo(xa.x), bf16hi(xa.x)};
            xlo2[1] = (f32x2){bf16lo(xa.y), bf16hi(xa.y)};
            xlo2[2] = (f32x2){bf16lo(xa.z), bf16hi(xa.z)};
            xlo2[3] = (f32x2){bf16lo(xa.w), bf16hi(xa.w)};
            xhi2[0] = (f32x2){bf16lo(xb.x), bf16hi(xb.x)};
            xhi2[1] = (f32x2){bf16lo(xb.y), bf16hi(xb.y)};
            xhi2[2] = (f32x2){bf16lo(xb.z), bf16hi(xb.z)};
            xhi2[3] = (f32x2){bf16lo(xb.w), bf16hi(xb.w)};
            #pragma unroll
            for (int j = 0; j < ROWS_PER_WAVE; ++j) {
                const uint32_t bv = ((uint32_t)qw[j][m]) & 0xFFu;
                const float flo = (float)((int)(bv << 28) >> 28);   // sext low nibble
                const float fhi = (float)((int)(bv << 24) >> 28);   // sext high nibble
                const f32x2 flo2 = (f32x2){flo, flo};
                const f32x2 fhi2 = (f32x2){fhi, fhi};
                #pragma unroll
                for (int p = 0; p < BATCH / 2; ++p) {
                    acc2[j][p] = __builtin_elementwise_fma(flo2, xlo2[p], acc2[j][p]);
                    acc2[j][p] = __builtin_elementwise_fma(fhi2, xhi2[p], acc2[j][p]);
                }
            }
        }
    };

    // ---- software-pipelined K loop (ping-pong, no copies) ----
    int4 qa[ROWS_PER_WAVE], qb[ROWS_PER_WAVE];
    qa[0] = wv0[lane]; qa[1] = wv1[lane]; qa[2] = wv2[lane]; qa[3] = wv3[lane];

    #pragma unroll 1
    for (int t = 0; t < ITERS; t += 2) {
        {
            const int un = ((t + 1) << 6) + lane;
            qb[0] = wv0[un]; qb[1] = wv1[un]; qb[2] = wv2[un]; qb[3] = wv3[un];
        }
        compute(qa, t);
        if (t + 2 < ITERS) {
            const int un = ((t + 2) << 6) + lane;
            qa[0] = wv0[un]; qa[1] = wv1[un]; qa[2] = wv2[un]; qa[3] = wv3[un];
        }
        compute(qb, t + 1);
    }

    // ---- 32-value tree reduction; value j*8+b lands on lane j*8+b ----
    float vals[32];
    #pragma unroll
    for (int j = 0; j < ROWS_PER_WAVE; ++j)
        #pragma unroll
        for (int p = 0; p < BATCH / 2; ++p) {
            vals[j * 8 + 2 * p]     = acc2[j][p].x;
            vals[j * 8 + 2 * p + 1] = acc2[j][p].y;
        }

    #pragma unroll
    for (int k = 0; k < 5; ++k) {
        const int sel = (lane >> k) & 1;
        const int n = 32 >> k;
        #pragma unroll
        for (int i = 0; i < n / 2; ++i) {
            const float a = vals[2 * i];
            const float c = vals[2 * i + 1];
            const float mine  = sel ? c : a;
            const float other = sel ? a : c;
            vals[i] = mine + __shfl_xor(other, 1 << k, 64);
        }
    }
    const float total = vals[0] + __shfl_xor(vals[0], 32, 64);

    if (lane < 32) {
        const int r = row0 + (lane >> 3);      // j = lane>>3, b = lane&7
        out[(size_t)(lane & 7) * N_DIM + r] = total * scales[r];
    }
}

extern "C" void kernel_launch(void* const* d_in, const int* in_sizes, int n_in,
                              void* d_out, int out_size, void* d_ws, size_t ws_size,
                              hipStream_t stream) {
    const float* x      = (const float*)d_in[0];
    const int*   w      = (const int*)d_in[1];
    const float* scales = (const float*)d_in[2];
    float*       out    = (float*)d_out;

    dim3 grid(N_DIM / ROWS_PER_BLOCK);   // 512
    dim3 block(BLOCK);                   // 512
    hipLaunchKernelGGL(w4a16_gemv, grid, block, 0, stream, x, w, scales, out);
}